// Round 14
// baseline (391.403 us; speedup 1.0000x reference)
//
#include <hip/hip_runtime.h>
#include <hip/hip_bf16.h>
#include <math.h>

#define DIMK 1024
#define NH 16
#define HD 64
#define BB 4
#define SS 8192
#define NKT 32  // K 1024 / BK=32

typedef __attribute__((ext_vector_type(8))) short bf16x8;
typedef __attribute__((ext_vector_type(8))) unsigned short ushort8;
typedef __attribute__((ext_vector_type(4))) unsigned short us4;
typedef __attribute__((ext_vector_type(4))) float f32x4;

#define MFMA16(a, b, c) __builtin_amdgcn_mfma_f32_16x16x32_bf16((a), (b), (c), 0, 0, 0)

__device__ __forceinline__ unsigned short f32_to_bf16_rne(float f) {
  unsigned int u = __float_as_uint(f);
  u = (u + 0x7fffu + ((u >> 16) & 1u)) >> 16;
  return (unsigned short)u;
}
__device__ __forceinline__ float bf16_bits_to_f32(unsigned short b) {
  return __uint_as_float(((unsigned int)b) << 16);
}
__device__ __forceinline__ void gload16(const void* g, void* l) {
  __builtin_amdgcn_global_load_lds((const __attribute__((address_space(1))) void*)g,
                                   (__attribute__((address_space(3))) void*)l, 16, 0, 0);
}

// ---------------- fill d_out with bo broadcast ----------------
__global__ __launch_bounds__(256) void fill_out_kernel(const float4* __restrict__ bo4,
                                                       float4* __restrict__ out, int total4) {
  for (int i = blockIdx.x * 256 + threadIdx.x; i < total4; i += gridDim.x * 256)
    out[i] = bo4[i & 255];
}

// ---------------- Wv / Wo fp32 -> tiled+swizzled bf16 hi/lo panels ----------------
__global__ __launch_bounds__(256) void prep_w2(
    const float* __restrict__ Wv, const float* __restrict__ Wo,
    unsigned short* __restrict__ Bkv, unsigned short* __restrict__ Bo) {
  const float* W = blockIdx.z ? Wo : Wv;
  unsigned short* Bpan = blockIdx.z ? Bo : Bkv;
  const int pnoff = blockIdx.z ? 0 : 8;
  __shared__ float st[64][65];
  const int bk = blockIdx.x * 64, bn = blockIdx.y * 64;
  const int t = threadIdx.x;
  const int lr = t >> 4, lc = (t & 15) * 4;
#pragma unroll
  for (int i = 0; i < 4; i++) {
    int k = lr + i * 16;
    float4 v = *(const float4*)(W + (size_t)(bk + k) * DIMK + bn + lc);
    st[k][lc] = v.x; st[k][lc + 1] = v.y; st[k][lc + 2] = v.z; st[k][lc + 3] = v.w;
  }
  __syncthreads();
  const int ktile = (bk + lc) >> 5, c = lc & 31;
#pragma unroll
  for (int i = 0; i < 4; i++) {
    const int nl = lr + i * 16;
    const int n = bn + nl;
    const int r = n & 127, pn = (n >> 7) + pnoff;
    const int q = (c >> 3) ^ ((r >> 1) & 3);
    const size_t byteoff = (size_t)r * 64 + q * 16 + (c & 7) * 2;
    us4 hv, lv;
#pragma unroll
    for (int j = 0; j < 4; j++) {
      float v = st[lc + j][nl];
      unsigned short hb = f32_to_bf16_rne(v);
      hv[j] = hb;
      lv[j] = f32_to_bf16_rne(v - bf16_bits_to_f32(hb));
    }
    char* base = (char*)Bpan;
    *(us4*)(base + (((size_t)pn * 64 + ktile) << 13) + byteoff) = hv;
    *(us4*)(base + (((size_t)pn * 64 + 32 + ktile) << 13) + byteoff) = lv;
  }
}

// ---------------- fold W1 into Wq/Wk ----------------
__global__ __launch_bounds__(256) void prep_wfold(
    const float* __restrict__ Wq, const float* __restrict__ Wk,
    const float* __restrict__ W1,
    unsigned short* __restrict__ Bq, unsigned short* __restrict__ Bkv) {
  const int which = blockIdx.z;
  const float* W = which ? Wk : Wq;
  unsigned short* Bpan = which ? Bkv : Bq;
  const int d_off = which ? 64 : 0;
  const int cc = blockIdx.x, jc = blockIdx.y;
  __shared__ float Wb[64][65];
  __shared__ float W1b[64][65];
  const int t = threadIdx.x;
  for (int idx = t; idx < 64 * 64; idx += 256) {
    int rrow = idx >> 6, dd = idx & 63;
    Wb[rrow][dd] = W[(size_t)(cc * 64 + rrow) * DIMK + jc * 64 + dd];
    W1b[rrow][dd] = W1[(size_t)(d_off + rrow) * 64 + dd];
  }
  __syncthreads();
  const int n = t & 63, g0 = t >> 6;
  const int pn = jc >> 1;
  const int r = (jc & 1) * 64 + n;
  const int sw = (r >> 1) & 3;
  char* base = (char*)Bpan;
#pragma unroll
  for (int i = 0; i < 4; ++i) {
    const int cl0 = (g0 + 4 * i) * 4;
    float a0 = 0.f, a1 = 0.f, a2 = 0.f, a3 = 0.f;
    for (int d = 0; d < 64; ++d) {
      const float w1v = W1b[d][n];
      a0 = fmaf(Wb[cl0 + 0][d], w1v, a0);
      a1 = fmaf(Wb[cl0 + 1][d], w1v, a1);
      a2 = fmaf(Wb[cl0 + 2][d], w1v, a2);
      a3 = fmaf(Wb[cl0 + 3][d], w1v, a3);
    }
    float av[4] = {a0, a1, a2, a3};
    const int c = cc * 64 + cl0;
    const int kt = c >> 5, kcol = c & 31;
    const int q = (kcol >> 3) ^ sw;
    const size_t byteoff = (size_t)r * 64 + q * 16 + (kcol & 7) * 2;
    us4 hv, lv;
#pragma unroll
    for (int j = 0; j < 4; j++) {
      unsigned short hb = f32_to_bf16_rne(av[j]);
      hv[j] = hb;
      lv[j] = f32_to_bf16_rne(av[j] - bf16_bits_to_f32(hb));
    }
    *(us4*)(base + (((size_t)pn * 64 + kt) << 13) + byteoff) = hv;
    *(us4*)(base + (((size_t)pn * 64 + 32 + kt) << 13) + byteoff) = lv;
  }
}

// ---------------- folded biases ----------------
__global__ __launch_bounds__(256) void prep_bias(
    const float* __restrict__ bq, const float* __restrict__ bk,
    const float* __restrict__ b1, const float* __restrict__ W1,
    float* __restrict__ bqf, float* __restrict__ bkf) {
  const int j = blockIdx.x * 256 + threadIdx.x;
  const int h = j >> 6, n = j & 63;
  float sq = 0.f, sk = 0.f;
  for (int d = 0; d < 64; ++d) {
    sq = fmaf(bq[h * 64 + d], W1[d * 64 + n], sq);
    sk = fmaf(bk[h * 64 + d], W1[(64 + d) * 64 + n], sk);
  }
  bqf[j] = sq;
  bkf[j] = sk + b1[n];
}

// ---------------- gather rows of X -> tiled+swizzled bf16 hi/lo A panels ----------------
__global__ __launch_bounds__(256) void prep_a(const float* __restrict__ X,
                                              const int* __restrict__ gidx,
                                              unsigned short* __restrict__ Apan, int M, int E) {
  const int row = blockIdx.x;
  const int r = row & 255, mt = row >> 8;
  const int c0 = threadIdx.x * 4;
  const int kt = c0 >> 5, c = c0 & 31;
  const int q = (c >> 3) ^ ((r >> 1) & 3);
  const size_t byteoff = (size_t)r * 64 + q * 16 + (c & 7) * 2;
  char* base = (char*)Apan;
  us4 hv = (us4){0, 0, 0, 0}, lv = (us4){0, 0, 0, 0};
  if (row < M) {
    const float* sr;
    if (gidx) {
      int b = row / E, e = row - b * E;
      sr = X + ((size_t)b * SS + gidx[e]) * DIMK;
    } else {
      sr = X + (size_t)row * DIMK;
    }
    float4 v = *(const float4*)(sr + c0);
    float vv[4] = {v.x, v.y, v.z, v.w};
#pragma unroll
    for (int i = 0; i < 4; i++) {
      unsigned short hb = f32_to_bf16_rne(vv[i]);
      hv[i] = hb;
      lv[i] = f32_to_bf16_rne(vv[i] - bf16_bits_to_f32(hb));
    }
  }
  *(us4*)(base + (((size_t)(mt * 64 + kt)) << 14) + byteoff) = hv;
  *(us4*)(base + (((size_t)(mt * 64 + 32 + kt)) << 14) + byteoff) = lv;
}

// ---------------- first-occurrence map ----------------
__global__ __launch_bounds__(1024) void first_occ(const int* __restrict__ src,
                                                  int* __restrict__ fidx,
                                                  int* __restrict__ mark, int E) {
  __shared__ int tbl[SS];
  for (int i = threadIdx.x; i < SS; i += 1024) tbl[i] = 0x7fffffff;
  __syncthreads();
  for (int e = threadIdx.x; e < E; e += 1024) atomicMin(&tbl[src[e]], e);
  __syncthreads();
  for (int e = threadIdx.x; e < E; e += 1024) mark[e] = 0;
  __syncthreads();
  for (int e = threadIdx.x; e < E; e += 1024) {
    int f = tbl[src[e]];
    fidx[e] = f;
    if (f != e) mark[f] = 1;
  }
}

// ---------------- 4-wave 128x128-per-wave GEMM (kv): min fragment redundancy ----------------
__global__ __launch_bounds__(256, 1) void gemmW(
    const unsigned short* __restrict__ Apan, const unsigned short* __restrict__ Bpan,
    const float* __restrict__ bias, const float* __restrict__ bias2,
    float* __restrict__ out, int ldc, int nty, int M, int E) {
  __shared__ unsigned short ldsAh[2][8192];
  __shared__ unsigned short ldsAl[2][8192];
  __shared__ unsigned short ldsBh[2][8192];
  __shared__ unsigned short ldsBl[2][8192];

  const int tid = threadIdx.x, lane = tid & 63, wv = tid >> 6;
  const int wr = wv >> 1, wc = wv & 1;

  const int w = (blockIdx.x & 7) * ((int)gridDim.x >> 3) + ((int)blockIdx.x >> 3);
  const int mi = w / nty, nt_ = w - mi * nty;
  const int m0 = mi * 256, n0 = nt_ * 256;

  const int rr = lane & 15, lq = lane >> 4;
  const int swz = (rr >> 1) & 3;
  const int aoff = wr * 4096 + rr * 32 + ((lq ^ swz) << 3);  // + mf*512
  const int boff = wc * 4096 + rr * 32 + ((lq ^ swz) << 3);  // + nf*512

  const char* Apb = (const char*)Apan + (((size_t)mi * 64) << 14);
  const char* Bpb = (const char*)Bpan;
  const int soff = (wv * 64 + lane) * 16;  // 0..4080

  f32x4 acc[8][8];
#pragma unroll
  for (int i = 0; i < 8; i++)
#pragma unroll
    for (int j = 0; j < 8; j++) acc[i][j] = (f32x4){0.f, 0.f, 0.f, 0.f};

  auto stage = [&](int kt, int buf) {
    const char* sAh = Apb + ((size_t)kt << 14);
    const char* sAl = Apb + ((size_t)(32 + kt) << 14);
#pragma unroll
    for (int s = 0; s < 4; ++s) {
      const int o = soff + s * 4096;
      gload16(sAh + o, &ldsAh[buf][o >> 1]);
      gload16(sAl + o, &ldsAl[buf][o >> 1]);
    }
    const char* sB0h = Bpb + (((size_t)(2 * nt_) * 64 + kt) << 13);
    const char* sB1h = Bpb + (((size_t)(2 * nt_ + 1) * 64 + kt) << 13);
    const char* sB0l = Bpb + (((size_t)(2 * nt_) * 64 + 32 + kt) << 13);
    const char* sB1l = Bpb + (((size_t)(2 * nt_ + 1) * 64 + 32 + kt) << 13);
#pragma unroll
    for (int s = 0; s < 2; ++s) {
      const int o = soff + s * 4096;
      gload16(sB0h + o, &ldsBh[buf][o >> 1]);
      gload16(sB1h + o, &ldsBh[buf][4096 + (o >> 1)]);
      gload16(sB0l + o, &ldsBl[buf][o >> 1]);
      gload16(sB1l + o, &ldsBl[buf][4096 + (o >> 1)]);
    }
  };

  stage(0, 0);
  asm volatile("s_waitcnt vmcnt(0)" ::: "memory");
  __builtin_amdgcn_sched_barrier(0);
  __builtin_amdgcn_s_barrier();

  for (int kt = 0; kt < NKT; ++kt) {
    const int buf = kt & 1;
    const unsigned short* Ah = ldsAh[buf];
    const unsigned short* Al = ldsAl[buf];
    const unsigned short* Bh = ldsBh[buf];
    const unsigned short* Bl = ldsBl[buf];

    bf16x8 fbh[8], fah[8], fal[8], fbl[8];
#pragma unroll
    for (int nf = 0; nf < 8; ++nf) fbh[nf] = *(const bf16x8*)(Bh + boff + nf * 512);
#pragma unroll
    for (int mf = 0; mf < 8; ++mf) fah[mf] = *(const bf16x8*)(Ah + aoff + mf * 512);
    __builtin_amdgcn_sched_barrier(0);
#pragma unroll
    for (int mf = 0; mf < 8; ++mf) fal[mf] = *(const bf16x8*)(Al + aoff + mf * 512);
    __builtin_amdgcn_sched_barrier(0);
#pragma unroll
    for (int nf = 0; nf < 8; ++nf) fbl[nf] = *(const bf16x8*)(Bl + boff + nf * 512);
    __builtin_amdgcn_sched_barrier(0);

    if (kt + 1 < NKT) stage(kt + 1, buf ^ 1);

    // C1: ah*bh (lgkmcnt field max 15; 15 allows fal(7 of 8)+fbl(8) outstanding)
    asm volatile("s_waitcnt lgkmcnt(15)" ::: "memory");
    __builtin_amdgcn_sched_barrier(0);
    __builtin_amdgcn_s_setprio(1);
#pragma unroll
    for (int mf = 0; mf < 8; ++mf)
#pragma unroll
      for (int nf = 0; nf < 8; ++nf) acc[mf][nf] = MFMA16(fah[mf], fbh[nf], acc[mf][nf]);
    __builtin_amdgcn_s_setprio(0);

    // C2: al*bh (outstanding: fbl 8)
    asm volatile("s_waitcnt lgkmcnt(8)" ::: "memory");
    __builtin_amdgcn_sched_barrier(0);
    __builtin_amdgcn_s_setprio(1);
#pragma unroll
    for (int mf = 0; mf < 8; ++mf)
#pragma unroll
      for (int nf = 0; nf < 8; ++nf) acc[mf][nf] = MFMA16(fal[mf], fbh[nf], acc[mf][nf]);
    __builtin_amdgcn_s_setprio(0);

    asm volatile("s_waitcnt lgkmcnt(0)" ::: "memory");
    if (kt + 1 < NKT) {
      asm volatile("s_waitcnt vmcnt(0)" ::: "memory");
      __builtin_amdgcn_sched_barrier(0);
      __builtin_amdgcn_s_barrier();
    } else {
      __builtin_amdgcn_sched_barrier(0);
    }

    // C3: ah*bl
    __builtin_amdgcn_s_setprio(1);
#pragma unroll
    for (int mf = 0; mf < 8; ++mf)
#pragma unroll
      for (int nf = 0; nf < 8; ++nf) acc[mf][nf] = MFMA16(fah[mf], fbl[nf], acc[mf][nf]);
    __builtin_amdgcn_s_setprio(0);
  }

  const int cq = lane >> 4, cr = lane & 15;
#pragma unroll
  for (int nf = 0; nf < 8; ++nf) {
    const int col = n0 + wc * 128 + nf * 16 + cr;
    const float bv = (bias2 != nullptr && col >= DIMK) ? bias2[col - DIMK]
                                                       : bias[col & (DIMK - 1)];
#pragma unroll
    for (int mf = 0; mf < 8; ++mf) {
#pragma unroll
      for (int r = 0; r < 4; ++r) {
        const int mrow = m0 + wr * 128 + mf * 16 + cq * 4 + r;
        if (mrow >= M) continue;
        out[(size_t)mrow * ldc + col] = acc[mf][nf][r] + bv;
      }
    }
  }
}

// ---------------- fused 3-term split-bf16 GEMM (R11 schedule), BM templated ----------------
template <int BM, int MODE>
__global__ __launch_bounds__(512, 2) void gemmT(
    const unsigned short* __restrict__ Apan, const unsigned short* __restrict__ Bpan,
    const float* __restrict__ bias, const float* __restrict__ bias2,
    float* __restrict__ out, int ldc, int nty,
    const int* __restrict__ fidx, const int* __restrict__ srci, int M, int E) {
  constexpr int MF = BM / 32;
  constexpr int NF = 4;
  constexpr int AT = BM * 32;
  __shared__ unsigned short ldsAh[2][AT];
  __shared__ unsigned short ldsAl[2][AT];
  __shared__ unsigned short ldsBh[2][8192];
  __shared__ unsigned short ldsBl[2][8192];

  const int tid = threadIdx.x, lane = tid & 63, wv = tid >> 6;
  const int wr = wv >> 2, wc = wv & 3;

  const int w = (blockIdx.x & 7) * ((int)gridDim.x >> 3) + ((int)blockIdx.x >> 3);
  const int mi = w / nty, nt_ = w - mi * nty;
  const int m0 = mi * BM, n0 = nt_ * 256;

  const int rr = lane & 15, lq = lane >> 4;
  const int swz = (rr >> 1) & 3;
  const int aoff = (wr * (BM / 2) + rr) * 32 + ((lq ^ swz) << 3);
  const int boff = (wc * 64 + rr) * 32 + ((lq ^ swz) << 3);

  const int pt = (BM == 256) ? mi : (mi >> 1);
  const int rowbase = (BM == 256) ? 0 : (mi & 1) * 128;
  const char* Apb = (const char*)Apan + (((size_t)pt * 64) << 14) + (size_t)rowbase * 64;
  const char* Bpb = (const char*)Bpan;
  const int stoff = wv * 1024 + lane * 16;

  f32x4 acc[MF][NF];
#pragma unroll
  for (int i = 0; i < MF; i++)
#pragma unroll
    for (int j = 0; j < NF; j++) acc[i][j] = (f32x4){0.f, 0.f, 0.f, 0.f};

  auto stage = [&](int kt, int buf) {
    const char* sAh = Apb + ((size_t)kt << 14) + stoff;
    const char* sAl = Apb + ((size_t)(32 + kt) << 14) + stoff;
    gload16(sAh, &ldsAh[buf][wv * 512]);
    gload16(sAl, &ldsAl[buf][wv * 512]);
    if (BM == 256) {
      gload16(sAh + 8192, &ldsAh[buf][wv * 512 + 4096]);
      gload16(sAl + 8192, &ldsAl[buf][wv * 512 + 4096]);
    }
    const char* sB0h = Bpb + (((size_t)(2 * nt_) * 64 + kt) << 13) + stoff;
    const char* sB1h = Bpb + (((size_t)(2 * nt_ + 1) * 64 + kt) << 13) + stoff;
    const char* sB0l = Bpb + (((size_t)(2 * nt_) * 64 + 32 + kt) << 13) + stoff;
    const char* sB1l = Bpb + (((size_t)(2 * nt_ + 1) * 64 + 32 + kt) << 13) + stoff;
    gload16(sB0h, &ldsBh[buf][wv * 512]);
    gload16(sB1h, &ldsBh[buf][wv * 512 + 4096]);
    gload16(sB0l, &ldsBl[buf][wv * 512]);
    gload16(sB1l, &ldsBl[buf][wv * 512 + 4096]);
  };

  stage(0, 0);
  asm volatile("s_waitcnt vmcnt(0)" ::: "memory");
  __builtin_amdgcn_sched_barrier(0);
  __builtin_amdgcn_s_barrier();

  for (int kt = 0; kt < NKT; ++kt) {
    const int buf = kt & 1;
    const unsigned short* Ah = ldsAh[buf];
    const unsigned short* Al = ldsAl[buf];
    const unsigned short* Bh = ldsBh[buf];
    const unsigned short* Bl = ldsBl[buf];

    bf16x8 fbh[NF], fah[MF], fal[MF], fbl[NF];
#pragma unroll
    for (int nf = 0; nf < NF; ++nf) fbh[nf] = *(const bf16x8*)(Bh + boff + nf * 512);
#pragma unroll
    for (int mf = 0; mf < MF; ++mf) fah[mf] = *(const bf16x8*)(Ah + aoff + mf * 512);
    __builtin_amdgcn_sched_barrier(0);
#pragma unroll
    for (int mf = 0; mf < MF; ++mf) fal[mf] = *(const bf16x8*)(Al + aoff + mf * 512);
    __builtin_amdgcn_sched_barrier(0);
#pragma unroll
    for (int nf = 0; nf < NF; ++nf) fbl[nf] = *(const bf16x8*)(Bl + boff + nf * 512);
    __builtin_amdgcn_sched_barrier(0);

    if (kt + 1 < NKT) stage(kt + 1, buf ^ 1);

    asm volatile("s_waitcnt lgkmcnt(%0)" ::"i"(MF + NF) : "memory");
    __builtin_amdgcn_sched_barrier(0);
    __builtin_amdgcn_s_setprio(1);
#pragma unroll
    for (int mf = 0; mf < MF; ++mf)
#pragma unroll
      for (int nf = 0; nf < NF; ++nf) acc[mf][nf] = MFMA16(fah[mf], fbh[nf], acc[mf][nf]);
    __builtin_amdgcn_s_setprio(0);

    asm volatile("s_waitcnt lgkmcnt(%0)" ::"i"(NF) : "memory");
    __builtin_amdgcn_sched_barrier(0);
    __builtin_amdgcn_s_setprio(1);
#pragma unroll
    for (int mf = 0; mf < MF; ++mf)
#pragma unroll
      for (int nf = 0; nf < NF; ++nf) acc[mf][nf] = MFMA16(fal[mf], fbh[nf], acc[mf][nf]);
    __builtin_amdgcn_s_setprio(0);

    asm volatile("s_waitcnt lgkmcnt(0)" ::: "memory");
    if (kt + 1 < NKT) {
      asm volatile("s_waitcnt vmcnt(0)" ::: "memory");
      __builtin_amdgcn_sched_barrier(0);
      __builtin_amdgcn_s_barrier();
    } else {
      __builtin_amdgcn_sched_barrier(0);
    }

    __builtin_amdgcn_s_setprio(1);
#pragma unroll
    for (int mf = 0; mf < MF; ++mf)
#pragma unroll
      for (int nf = 0; nf < NF; ++nf) acc[mf][nf] = MFMA16(fah[mf], fbl[nf], acc[mf][nf]);
    __builtin_amdgcn_s_setprio(0);
  }

  const int cq = lane >> 4, cr = lane & 15;
#pragma unroll
  for (int nf = 0; nf < NF; ++nf) {
    const int col = n0 + wc * 64 + nf * 16 + cr;
    const float bv = (MODE == 0 && bias2 != nullptr && col >= DIMK) ? bias2[col - DIMK]
                                                                    : bias[col & (DIMK - 1)];
#pragma unroll
    for (int mf = 0; mf < MF; ++mf) {
#pragma unroll
      for (int r = 0; r < 4; ++r) {
        const int mrow = m0 + wr * (BM / 2) + mf * 16 + cq * 4 + r;
        if (mrow >= M) continue;
        if (MODE == 0) {
          out[(size_t)mrow * ldc + col] = acc[mf][nf][r] + bv;
        } else {
          int b = mrow / E, e = mrow - b * E;
          if (fidx[e] == e) {
            int orow = b * SS + srci[e];
            out[(size_t)orow * ldc + col] = acc[mf][nf][r] + bv;
          }
        }
      }
    }
  }
}

// ---------------- edge scores from folded pre-activations ----------------
__global__ __launch_bounds__(256) void edge_scores_f(
    const float* __restrict__ hq, const float* __restrict__ hk,
    const float* __restrict__ W2, const float* __restrict__ b2,
    float* __restrict__ scores, int E, int CH) {
  const int tid = threadIdx.x, lane = tid & 63, w = tid >> 6;
  const int bh = blockIdx.x / CH, ch = blockIdx.x - bh * CH;
  const int b = bh >> 4, h = bh & 15;
  const float w2 = W2[lane];
  const float b2v = b2[0];
#pragma unroll
  for (int i = 0; i < 8; ++i) {
    const int e = ch * 32 + w * 8 + i;
    if (e >= E) break;
    const size_t row = (size_t)(b * E + e);
    float hv = hq[row * 1024 + h * 64 + lane] + hk[row * 2048 + h * 64 + lane];
    hv = 0.5f * hv * (1.f + erff(hv * 0.70710678118654752f));
    float p = hv * w2;
#pragma unroll
    for (int off = 32; off; off >>= 1) p += __shfl_xor(p, off, 64);
    if (lane == 0) scores[(size_t)(b * NH + h) * E + e] = (p + b2v) * 0.125f;
  }
}

// ---------------- softmax over E per (b,h), then *= edge_weight[h] ----------------
__global__ __launch_bounds__(256) void softmax_ew(float* __restrict__ scores,
                                                  const float* __restrict__ ew, int E) {
  const int row = blockIdx.x;
  const int h = row & (NH - 1);
  float* s = scores + (size_t)row * E;
  const int tid = threadIdx.x, lane = tid & 63, w = tid >> 6;
  __shared__ float red[4];

  float vals[8];
  float mx = -1e30f;
#pragma unroll
  for (int i = 0; i < 8; i++) {
    int j = tid + i * 256;
    vals[i] = (j < E) ? s[j] : -1e30f;
    mx = fmaxf(mx, vals[i]);
  }
#pragma unroll
  for (int off = 32; off; off >>= 1) mx = fmaxf(mx, __shfl_xor(mx, off, 64));
  if (lane == 0) red[w] = mx;
  __syncthreads();
  mx = fmaxf(fmaxf(red[0], red[1]), fmaxf(red[2], red[3]));
  __syncthreads();

  float sum = 0.f;
#pragma unroll
  for (int i = 0; i < 8; i++) {
    vals[i] = __expf(vals[i] - mx);
    if (tid + i * 256 < E) sum += vals[i];
  }
#pragma unroll
  for (int off = 32; off; off >>= 1) sum += __shfl_xor(sum, off, 64);
  if (lane == 0) red[w] = sum;
  __syncthreads();
  sum = red[0] + red[1] + red[2] + red[3];

  const float scaleout = ew[h] / sum;
#pragma unroll
  for (int i = 0; i < 8; i++) {
    int j = tid + i * 256;
    if (j < E) s[j] = vals[i] * scaleout;
  }
}

// ---------------- weight rows (attn * v) + write fp32 wrow + split A panels ----------------
__global__ __launch_bounds__(256) void weight_split(
    const float* __restrict__ vd, int ldv, const float* __restrict__ attn,
    float* __restrict__ wrow, unsigned short* __restrict__ Apan, int M, int E) {
  const int row = blockIdx.x;
  const int r = row & 255, mt = row >> 8;
  const int c0 = threadIdx.x * 4;
  const int kt = c0 >> 5, c = c0 & 31;
  const int q = (c >> 3) ^ ((r >> 1) & 3);
  const size_t byteoff = (size_t)r * 64 + q * 16 + (c & 7) * 2;
  char* base = (char*)Apan;
  us4 hv = (us4){0, 0, 0, 0}, lv = (us4){0, 0, 0, 0};
  if (row < M) {
    const int b = row / E, e = row - b * E;
    const float a = attn[(size_t)(b * NH + (c0 >> 6)) * E + e];
    float4 v = *(const float4*)(vd + (size_t)row * ldv + c0);
    v.x *= a; v.y *= a; v.z *= a; v.w *= a;
    *(float4*)(wrow + (size_t)row * DIMK + c0) = v;
    float vv[4] = {v.x, v.y, v.z, v.w};
#pragma unroll
    for (int i = 0; i < 4; i++) {
      unsigned short hb = f32_to_bf16_rne(vv[i]);
      hv[i] = hb;
      lv[i] = f32_to_bf16_rne(vv[i] - bf16_bits_to_f32(hb));
    }
  }
  *(us4*)(base + (((size_t)(mt * 64 + kt)) << 14) + byteoff) = hv;
  *(us4*)(base + (((size_t)(mt * 64 + 32 + kt)) << 14) + byteoff) = lv;
}

// ---------------- fold duplicate-src edges into primary rows ----------------
__global__ __launch_bounds__(256) void dup_add(const int* __restrict__ f,
                                               float* __restrict__ wrow, int E) {
  const int e = blockIdx.x;
  const int fe = f[e];
  if (fe == e) return;
  const int d = threadIdx.x * 4;
#pragma unroll
  for (int b = 0; b < BB; b++) {
    const float4 v = *(const float4*)(wrow + (size_t)(b * E + e) * DIMK + d);
    float* dst = wrow + (size_t)(b * E + fe) * DIMK + d;
    atomicAdd(dst + 0, v.x);
    atomicAdd(dst + 1, v.y);
    atomicAdd(dst + 2, v.z);
    atomicAdd(dst + 3, v.w);
  }
}

// ---------------- re-split panels for primary rows that received duplicates ----------------
__global__ __launch_bounds__(256) void dup_fix(const int* __restrict__ fidx,
                                               const int* __restrict__ mark,
                                               const float* __restrict__ wrow,
                                               unsigned short* __restrict__ Apan, int E) {
  const int e = blockIdx.x;
  if (fidx[e] != e || !mark[e]) return;
  const int c0 = threadIdx.x * 4;
  const int kt = c0 >> 5, c = c0 & 31;
  char* base = (char*)Apan;
  for (int b = 0; b < BB; b++) {
    const int row = b * E + e;
    const int r = row & 255, mt = row >> 8;
    const int q = (c >> 3) ^ ((r >> 1) & 3);
    const size_t byteoff = (size_t)r * 64 + q * 16 + (c & 7) * 2;
    float4 v = *(const float4*)(wrow + (size_t)row * DIMK + c0);
    float vv[4] = {v.x, v.y, v.z, v.w};
    us4 hv, lv;
#pragma unroll
    for (int i = 0; i < 4; i++) {
      unsigned short hb = f32_to_bf16_rne(vv[i]);
      hv[i] = hb;
      lv[i] = f32_to_bf16_rne(vv[i] - bf16_bits_to_f32(hb));
    }
    *(us4*)(base + (((size_t)(mt * 64 + kt)) << 14) + byteoff) = hv;
    *(us4*)(base + (((size_t)(mt * 64 + 32 + kt)) << 14) + byteoff) = lv;
  }
}

extern "C" void kernel_launch(void* const* d_in, const int* in_sizes, int n_in,
                              void* d_out, int out_size, void* d_ws, size_t ws_size,
                              hipStream_t stream) {
  const float* x = (const float*)d_in[0];
  const int* src = (const int*)d_in[1];
  const int* dst = (const int*)d_in[2];
  const float* Wq = (const float*)d_in[3];
  const float* bq = (const float*)d_in[4];
  const float* Wk = (const float*)d_in[5];
  const float* bk = (const float*)d_in[6];
  const float* Wv = (const float*)d_in[7];
  const float* bv = (const float*)d_in[8];
  const float* Wo = (const float*)d_in[9];
  const float* bo = (const float*)d_in[10];
  const float* ew = (const float*)d_in[11];
  const float* W1 = (const float*)d_in[12];
  const float* b1 = (const float*)d_in[13];
  const float* W2 = (const float*)d_in[14];
  const float* b2 = (const float*)d_in[15];
  float* out = (float*)d_out;

  const int E = in_sizes[1];
  const int M = BB * E;
  const int gx = (M + 255) / 256;
  const int Mpad = gx * 256;
  const int mi128 = gx * 2;

  char* w = (char*)d_ws;
  float* qs = (float*)w; w += (size_t)M * DIMK * 4;
  float* kv = (float*)w; w += (size_t)M * 2048 * 4;
  float* sc = (float*)w; w += (size_t)BB * NH * E * 4;
  int* fidx = (int*)w; w += (((size_t)E * 4) + 255) & ~(size_t)255;
  int* mark = (int*)w; w += (((size_t)E * 4) + 255) & ~(size_t)255;
  float* bqf = (float*)w; w += 1024 * 4;
  float* bkf = (float*)w; w += 1024 * 4;
  unsigned short* Bq = (unsigned short*)w; w += (size_t)8 * 64 * 8192;
  unsigned short* Bkv = (unsigned short*)w; w += (size_t)16 * 64 * 8192;
  unsigned short* Bo = (unsigned short*)w; w += (size_t)8 * 64 * 8192;
  unsigned short* Apan = (unsigned short*)w; w += (size_t)gx * 64 * 16384;

  float* wrow = qs;

  // 1) fill output with bo
  const int total4 = BB * SS * (DIMK / 4);
  fill_out_kernel<<<2048, 256, 0, stream>>>((const float4*)bo, (float4*)out, total4);

  // 2) weight prep
  prep_w2<<<dim3(16, 16, 2), 256, 0, stream>>>(Wv, Wo, Bkv, Bo);
  prep_wfold<<<dim3(16, 16, 2), 256, 0, stream>>>(Wq, Wk, W1, Bq, Bkv);
  prep_bias<<<4, 256, 0, stream>>>(bq, bk, b1, W1, bqf, bkf);

  // 3) first-occurrence map + dup marks
  first_occ<<<1, 1024, 0, stream>>>(src, fidx, mark, E);

  // 4) q-part of h_pre: x_src @ WQ1 + bqf (BM=128 8-wave, grid 256)
  prep_a<<<Mpad, 256, 0, stream>>>(x, src, Apan, M, E);
  gemmT<128, 0><<<mi128 * 4, 512, 0, stream>>>(Apan, Bq, bqf, nullptr, qs, DIMK, 4,
                                               nullptr, nullptr, M, E);

  // 5) [k-part of h_pre | v]: x_dst @ [WK1 | Wv] (4-wave 128x128 wave-tiles, grid 256)
  prep_a<<<Mpad, 256, 0, stream>>>(x, dst, Apan, M, E);
  gemmW<<<gx * 8, 256, 0, stream>>>(Apan, Bkv, bkf, bv, kv, 2048, 8, M, E);

  // 6) edge scores (gelu + W2 dot), softmax + edge_weight
  const int CH = (E + 31) / 32;
  edge_scores_f<<<BB * NH * CH, 256, 0, stream>>>(qs, kv, W2, b2, sc, E, CH);
  softmax_ew<<<BB * NH, 256, 0, stream>>>(sc, ew, E);

  // 7) weighted rows + split panels; fold duplicates; re-split affected rows
  weight_split<<<Mpad, 256, 0, stream>>>(kv + 1024, 2048, sc, wrow, Apan, M, E);
  dup_add<<<E, 256, 0, stream>>>(fidx, wrow, E);
  dup_fix<<<E, 256, 0, stream>>>(fidx, mark, wrow, Apan, E);

  // 8) final GEMM: wrow @ Wo, guarded scatter-store (BM=128 8-wave, grid 256)
  gemmT<128, 1><<<mi128 * 4, 512, 0, stream>>>(Apan, Bo, bo, nullptr, out, DIMK, 4,
                                               fidx, src, M, E);
}

// Round 15
// 334.785 us; speedup vs baseline: 1.1691x; 1.1691x over previous
//
#include <hip/hip_runtime.h>
#include <hip/hip_bf16.h>
#include <math.h>

#define DIMK 1024
#define NH 16
#define HD 64
#define BB 4
#define SS 8192
#define NKT 32  // K 1024 / BK=32

typedef __attribute__((ext_vector_type(8))) short bf16x8;
typedef __attribute__((ext_vector_type(8))) unsigned short ushort8;
typedef __attribute__((ext_vector_type(4))) unsigned short us4;
typedef __attribute__((ext_vector_type(4))) float f32x4;

#define MFMA16(a, b, c) __builtin_amdgcn_mfma_f32_16x16x32_bf16((a), (b), (c), 0, 0, 0)

__device__ __forceinline__ unsigned short f32_to_bf16_rne(float f) {
  unsigned int u = __float_as_uint(f);
  u = (u + 0x7fffu + ((u >> 16) & 1u)) >> 16;
  return (unsigned short)u;
}
__device__ __forceinline__ float bf16_bits_to_f32(unsigned short b) {
  return __uint_as_float(((unsigned int)b) << 16);
}
__device__ __forceinline__ void gload16(const void* g, void* l) {
  __builtin_amdgcn_global_load_lds((const __attribute__((address_space(1))) void*)g,
                                   (__attribute__((address_space(3))) void*)l, 16, 0, 0);
}

// ---------------- fill d_out with bo broadcast ----------------
__global__ __launch_bounds__(256) void fill_out_kernel(const float4* __restrict__ bo4,
                                                       float4* __restrict__ out, int total4) {
  for (int i = blockIdx.x * 256 + threadIdx.x; i < total4; i += gridDim.x * 256)
    out[i] = bo4[i & 255];
}

// ---------------- Wv / Wo fp32 -> tiled+swizzled bf16 hi/lo panels ----------------
__global__ __launch_bounds__(256) void prep_w2(
    const float* __restrict__ Wv, const float* __restrict__ Wo,
    unsigned short* __restrict__ Bkv, unsigned short* __restrict__ Bo) {
  const float* W = blockIdx.z ? Wo : Wv;
  unsigned short* Bpan = blockIdx.z ? Bo : Bkv;
  const int pnoff = blockIdx.z ? 0 : 8;
  __shared__ float st[64][65];
  const int bk = blockIdx.x * 64, bn = blockIdx.y * 64;
  const int t = threadIdx.x;
  const int lr = t >> 4, lc = (t & 15) * 4;
#pragma unroll
  for (int i = 0; i < 4; i++) {
    int k = lr + i * 16;
    float4 v = *(const float4*)(W + (size_t)(bk + k) * DIMK + bn + lc);
    st[k][lc] = v.x; st[k][lc + 1] = v.y; st[k][lc + 2] = v.z; st[k][lc + 3] = v.w;
  }
  __syncthreads();
  const int ktile = (bk + lc) >> 5, c = lc & 31;
#pragma unroll
  for (int i = 0; i < 4; i++) {
    const int nl = lr + i * 16;
    const int n = bn + nl;
    const int r = n & 127, pn = (n >> 7) + pnoff;
    const int q = (c >> 3) ^ ((r >> 1) & 3);
    const size_t byteoff = (size_t)r * 64 + q * 16 + (c & 7) * 2;
    us4 hv, lv;
#pragma unroll
    for (int j = 0; j < 4; j++) {
      float v = st[lc + j][nl];
      unsigned short hb = f32_to_bf16_rne(v);
      hv[j] = hb;
      lv[j] = f32_to_bf16_rne(v - bf16_bits_to_f32(hb));
    }
    char* base = (char*)Bpan;
    *(us4*)(base + (((size_t)pn * 64 + ktile) << 13) + byteoff) = hv;
    *(us4*)(base + (((size_t)pn * 64 + 32 + ktile) << 13) + byteoff) = lv;
  }
}

// ---------------- fold W1 into Wq/Wk ----------------
__global__ __launch_bounds__(256) void prep_wfold(
    const float* __restrict__ Wq, const float* __restrict__ Wk,
    const float* __restrict__ W1,
    unsigned short* __restrict__ Bq, unsigned short* __restrict__ Bkv) {
  const int which = blockIdx.z;
  const float* W = which ? Wk : Wq;
  unsigned short* Bpan = which ? Bkv : Bq;
  const int d_off = which ? 64 : 0;
  const int cc = blockIdx.x, jc = blockIdx.y;
  __shared__ float Wb[64][65];
  __shared__ float W1b[64][65];
  const int t = threadIdx.x;
  for (int idx = t; idx < 64 * 64; idx += 256) {
    int rrow = idx >> 6, dd = idx & 63;
    Wb[rrow][dd] = W[(size_t)(cc * 64 + rrow) * DIMK + jc * 64 + dd];
    W1b[rrow][dd] = W1[(size_t)(d_off + rrow) * 64 + dd];
  }
  __syncthreads();
  const int n = t & 63, g0 = t >> 6;
  const int pn = jc >> 1;
  const int r = (jc & 1) * 64 + n;
  const int sw = (r >> 1) & 3;
  char* base = (char*)Bpan;
#pragma unroll
  for (int i = 0; i < 4; ++i) {
    const int cl0 = (g0 + 4 * i) * 4;
    float a0 = 0.f, a1 = 0.f, a2 = 0.f, a3 = 0.f;
    for (int d = 0; d < 64; ++d) {
      const float w1v = W1b[d][n];
      a0 = fmaf(Wb[cl0 + 0][d], w1v, a0);
      a1 = fmaf(Wb[cl0 + 1][d], w1v, a1);
      a2 = fmaf(Wb[cl0 + 2][d], w1v, a2);
      a3 = fmaf(Wb[cl0 + 3][d], w1v, a3);
    }
    float av[4] = {a0, a1, a2, a3};
    const int c = cc * 64 + cl0;
    const int kt = c >> 5, kcol = c & 31;
    const int q = (kcol >> 3) ^ sw;
    const size_t byteoff = (size_t)r * 64 + q * 16 + (kcol & 7) * 2;
    us4 hv, lv;
#pragma unroll
    for (int j = 0; j < 4; j++) {
      unsigned short hb = f32_to_bf16_rne(av[j]);
      hv[j] = hb;
      lv[j] = f32_to_bf16_rne(av[j] - bf16_bits_to_f32(hb));
    }
    *(us4*)(base + (((size_t)pn * 64 + kt) << 13) + byteoff) = hv;
    *(us4*)(base + (((size_t)pn * 64 + 32 + kt) << 13) + byteoff) = lv;
  }
}

// ---------------- folded biases ----------------
__global__ __launch_bounds__(256) void prep_bias(
    const float* __restrict__ bq, const float* __restrict__ bk,
    const float* __restrict__ b1, const float* __restrict__ W1,
    float* __restrict__ bqf, float* __restrict__ bkf) {
  const int j = blockIdx.x * 256 + threadIdx.x;
  const int h = j >> 6, n = j & 63;
  float sq = 0.f, sk = 0.f;
  for (int d = 0; d < 64; ++d) {
    sq = fmaf(bq[h * 64 + d], W1[d * 64 + n], sq);
    sk = fmaf(bk[h * 64 + d], W1[(64 + d) * 64 + n], sk);
  }
  bqf[j] = sq;
  bkf[j] = sk + b1[n];
}

// ---------------- gather rows of X -> tiled+swizzled bf16 hi/lo A panels ----------------
__global__ __launch_bounds__(256) void prep_a(const float* __restrict__ X,
                                              const int* __restrict__ gidx,
                                              unsigned short* __restrict__ Apan, int M, int E) {
  const int row = blockIdx.x;
  const int r = row & 255, mt = row >> 8;
  const int c0 = threadIdx.x * 4;
  const int kt = c0 >> 5, c = c0 & 31;
  const int q = (c >> 3) ^ ((r >> 1) & 3);
  const size_t byteoff = (size_t)r * 64 + q * 16 + (c & 7) * 2;
  char* base = (char*)Apan;
  us4 hv = (us4){0, 0, 0, 0}, lv = (us4){0, 0, 0, 0};
  if (row < M) {
    const float* sr;
    if (gidx) {
      int b = row / E, e = row - b * E;
      sr = X + ((size_t)b * SS + gidx[e]) * DIMK;
    } else {
      sr = X + (size_t)row * DIMK;
    }
    float4 v = *(const float4*)(sr + c0);
    float vv[4] = {v.x, v.y, v.z, v.w};
#pragma unroll
    for (int i = 0; i < 4; i++) {
      unsigned short hb = f32_to_bf16_rne(vv[i]);
      hv[i] = hb;
      lv[i] = f32_to_bf16_rne(vv[i] - bf16_bits_to_f32(hb));
    }
  }
  *(us4*)(base + (((size_t)(mt * 64 + kt)) << 14) + byteoff) = hv;
  *(us4*)(base + (((size_t)(mt * 64 + 32 + kt)) << 14) + byteoff) = lv;
}

// ---------------- first-occurrence map ----------------
__global__ __launch_bounds__(1024) void first_occ(const int* __restrict__ src,
                                                  int* __restrict__ fidx,
                                                  int* __restrict__ mark, int E) {
  __shared__ int tbl[SS];
  for (int i = threadIdx.x; i < SS; i += 1024) tbl[i] = 0x7fffffff;
  __syncthreads();
  for (int e = threadIdx.x; e < E; e += 1024) atomicMin(&tbl[src[e]], e);
  __syncthreads();
  for (int e = threadIdx.x; e < E; e += 1024) mark[e] = 0;
  __syncthreads();
  for (int e = threadIdx.x; e < E; e += 1024) {
    int f = tbl[src[e]];
    fidx[e] = f;
    if (f != e) mark[f] = 1;
  }
}

// ---------------- fused 3-term split-bf16 GEMM (R11 schedule), BM templated ----------------
// BN=256 always. BM=256: panel per m-tile. BM=128: two m-tiles share a 256-row panel
// (rowbase = (mi&1)*128). All fragment reads upfront in pinned groups; counted lgkmcnt;
// vmcnt(0)+barrier before cluster 3 (barrier shadow covered by C3's MFMAs).
template <int BM, int MODE>
__global__ __launch_bounds__(512, 2) void gemmT(
    const unsigned short* __restrict__ Apan, const unsigned short* __restrict__ Bpan,
    const float* __restrict__ bias, const float* __restrict__ bias2,
    float* __restrict__ out, int ldc, int nty,
    const int* __restrict__ fidx, const int* __restrict__ srci, int M, int E) {
  constexpr int MF = BM / 32;
  constexpr int NF = 4;
  constexpr int AT = BM * 32;
  __shared__ unsigned short ldsAh[2][AT];
  __shared__ unsigned short ldsAl[2][AT];
  __shared__ unsigned short ldsBh[2][8192];
  __shared__ unsigned short ldsBl[2][8192];

  const int tid = threadIdx.x, lane = tid & 63, wv = tid >> 6;
  const int wr = wv >> 2, wc = wv & 3;

  const int w = (blockIdx.x & 7) * ((int)gridDim.x >> 3) + ((int)blockIdx.x >> 3);
  const int mi = w / nty, nt_ = w - mi * nty;
  const int m0 = mi * BM, n0 = nt_ * 256;

  const int rr = lane & 15, lq = lane >> 4;
  const int swz = (rr >> 1) & 3;
  const int aoff = (wr * (BM / 2) + rr) * 32 + ((lq ^ swz) << 3);
  const int boff = (wc * 64 + rr) * 32 + ((lq ^ swz) << 3);

  const int pt = (BM == 256) ? mi : (mi >> 1);
  const int rowbase = (BM == 256) ? 0 : (mi & 1) * 128;
  const char* Apb = (const char*)Apan + (((size_t)pt * 64) << 14) + (size_t)rowbase * 64;
  const char* Bpb = (const char*)Bpan;
  const int stoff = wv * 1024 + lane * 16;

  f32x4 acc[MF][NF];
#pragma unroll
  for (int i = 0; i < MF; i++)
#pragma unroll
    for (int j = 0; j < NF; j++) acc[i][j] = (f32x4){0.f, 0.f, 0.f, 0.f};

  auto stage = [&](int kt, int buf) {
    const char* sAh = Apb + ((size_t)kt << 14) + stoff;
    const char* sAl = Apb + ((size_t)(32 + kt) << 14) + stoff;
    gload16(sAh, &ldsAh[buf][wv * 512]);
    gload16(sAl, &ldsAl[buf][wv * 512]);
    if (BM == 256) {
      gload16(sAh + 8192, &ldsAh[buf][wv * 512 + 4096]);
      gload16(sAl + 8192, &ldsAl[buf][wv * 512 + 4096]);
    }
    const char* sB0h = Bpb + (((size_t)(2 * nt_) * 64 + kt) << 13) + stoff;
    const char* sB1h = Bpb + (((size_t)(2 * nt_ + 1) * 64 + kt) << 13) + stoff;
    const char* sB0l = Bpb + (((size_t)(2 * nt_) * 64 + 32 + kt) << 13) + stoff;
    const char* sB1l = Bpb + (((size_t)(2 * nt_ + 1) * 64 + 32 + kt) << 13) + stoff;
    gload16(sB0h, &ldsBh[buf][wv * 512]);
    gload16(sB1h, &ldsBh[buf][wv * 512 + 4096]);
    gload16(sB0l, &ldsBl[buf][wv * 512]);
    gload16(sB1l, &ldsBl[buf][wv * 512 + 4096]);
  };

  stage(0, 0);
  asm volatile("s_waitcnt vmcnt(0)" ::: "memory");
  __builtin_amdgcn_sched_barrier(0);
  __builtin_amdgcn_s_barrier();

  for (int kt = 0; kt < NKT; ++kt) {
    const int buf = kt & 1;
    const unsigned short* Ah = ldsAh[buf];
    const unsigned short* Al = ldsAl[buf];
    const unsigned short* Bh = ldsBh[buf];
    const unsigned short* Bl = ldsBl[buf];

    bf16x8 fbh[NF], fah[MF], fal[MF], fbl[NF];
#pragma unroll
    for (int nf = 0; nf < NF; ++nf) fbh[nf] = *(const bf16x8*)(Bh + boff + nf * 512);
#pragma unroll
    for (int mf = 0; mf < MF; ++mf) fah[mf] = *(const bf16x8*)(Ah + aoff + mf * 512);
    __builtin_amdgcn_sched_barrier(0);
#pragma unroll
    for (int mf = 0; mf < MF; ++mf) fal[mf] = *(const bf16x8*)(Al + aoff + mf * 512);
    __builtin_amdgcn_sched_barrier(0);
#pragma unroll
    for (int nf = 0; nf < NF; ++nf) fbl[nf] = *(const bf16x8*)(Bl + boff + nf * 512);
    __builtin_amdgcn_sched_barrier(0);

    if (kt + 1 < NKT) stage(kt + 1, buf ^ 1);

    asm volatile("s_waitcnt lgkmcnt(%0)" ::"i"(MF + NF) : "memory");
    __builtin_amdgcn_sched_barrier(0);
    __builtin_amdgcn_s_setprio(1);
#pragma unroll
    for (int mf = 0; mf < MF; ++mf)
#pragma unroll
      for (int nf = 0; nf < NF; ++nf) acc[mf][nf] = MFMA16(fah[mf], fbh[nf], acc[mf][nf]);
    __builtin_amdgcn_s_setprio(0);

    asm volatile("s_waitcnt lgkmcnt(%0)" ::"i"(NF) : "memory");
    __builtin_amdgcn_sched_barrier(0);
    __builtin_amdgcn_s_setprio(1);
#pragma unroll
    for (int mf = 0; mf < MF; ++mf)
#pragma unroll
      for (int nf = 0; nf < NF; ++nf) acc[mf][nf] = MFMA16(fal[mf], fbh[nf], acc[mf][nf]);
    __builtin_amdgcn_s_setprio(0);

    asm volatile("s_waitcnt lgkmcnt(0)" ::: "memory");
    if (kt + 1 < NKT) {
      asm volatile("s_waitcnt vmcnt(0)" ::: "memory");
      __builtin_amdgcn_sched_barrier(0);
      __builtin_amdgcn_s_barrier();
    } else {
      __builtin_amdgcn_sched_barrier(0);
    }

    __builtin_amdgcn_s_setprio(1);
#pragma unroll
    for (int mf = 0; mf < MF; ++mf)
#pragma unroll
      for (int nf = 0; nf < NF; ++nf) acc[mf][nf] = MFMA16(fah[mf], fbl[nf], acc[mf][nf]);
    __builtin_amdgcn_s_setprio(0);
  }

  const int cq = lane >> 4, cr = lane & 15;
#pragma unroll
  for (int nf = 0; nf < NF; ++nf) {
    const int col = n0 + wc * 64 + nf * 16 + cr;
    const float bv = (MODE == 0 && bias2 != nullptr && col >= DIMK) ? bias2[col - DIMK]
                                                                    : bias[col & (DIMK - 1)];
#pragma unroll
    for (int mf = 0; mf < MF; ++mf) {
#pragma unroll
      for (int r = 0; r < 4; ++r) {
        const int mrow = m0 + wr * (BM / 2) + mf * 16 + cq * 4 + r;
        if (mrow >= M) continue;
        if (MODE == 0) {
          out[(size_t)mrow * ldc + col] = acc[mf][nf][r] + bv;
        } else {
          int b = mrow / E, e = mrow - b * E;
          if (fidx[e] == e) {
            int orow = b * SS + srci[e];
            out[(size_t)orow * ldc + col] = acc[mf][nf][r] + bv;
          }
        }
      }
    }
  }
}

// ---------------- edge scores from folded pre-activations ----------------
__global__ __launch_bounds__(256) void edge_scores_f(
    const float* __restrict__ hq, const float* __restrict__ hk,
    const float* __restrict__ W2, const float* __restrict__ b2,
    float* __restrict__ scores, int E, int CH) {
  const int tid = threadIdx.x, lane = tid & 63, w = tid >> 6;
  const int bh = blockIdx.x / CH, ch = blockIdx.x - bh * CH;
  const int b = bh >> 4, h = bh & 15;
  const float w2 = W2[lane];
  const float b2v = b2[0];
#pragma unroll
  for (int i = 0; i < 8; ++i) {
    const int e = ch * 32 + w * 8 + i;
    if (e >= E) break;
    const size_t row = (size_t)(b * E + e);
    float hv = hq[row * 1024 + h * 64 + lane] + hk[row * 2048 + h * 64 + lane];
    hv = 0.5f * hv * (1.f + erff(hv * 0.70710678118654752f));
    float p = hv * w2;
#pragma unroll
    for (int off = 32; off; off >>= 1) p += __shfl_xor(p, off, 64);
    if (lane == 0) scores[(size_t)(b * NH + h) * E + e] = (p + b2v) * 0.125f;
  }
}

// ---------------- softmax over E per (b,h), then *= edge_weight[h] ----------------
__global__ __launch_bounds__(256) void softmax_ew(float* __restrict__ scores,
                                                  const float* __restrict__ ew, int E) {
  const int row = blockIdx.x;
  const int h = row & (NH - 1);
  float* s = scores + (size_t)row * E;
  const int tid = threadIdx.x, lane = tid & 63, w = tid >> 6;
  __shared__ float red[4];

  float vals[8];
  float mx = -1e30f;
#pragma unroll
  for (int i = 0; i < 8; i++) {
    int j = tid + i * 256;
    vals[i] = (j < E) ? s[j] : -1e30f;
    mx = fmaxf(mx, vals[i]);
  }
#pragma unroll
  for (int off = 32; off; off >>= 1) mx = fmaxf(mx, __shfl_xor(mx, off, 64));
  if (lane == 0) red[w] = mx;
  __syncthreads();
  mx = fmaxf(fmaxf(red[0], red[1]), fmaxf(red[2], red[3]));
  __syncthreads();

  float sum = 0.f;
#pragma unroll
  for (int i = 0; i < 8; i++) {
    vals[i] = __expf(vals[i] - mx);
    if (tid + i * 256 < E) sum += vals[i];
  }
#pragma unroll
  for (int off = 32; off; off >>= 1) sum += __shfl_xor(sum, off, 64);
  if (lane == 0) red[w] = sum;
  __syncthreads();
  sum = red[0] + red[1] + red[2] + red[3];

  const float scaleout = ew[h] / sum;
#pragma unroll
  for (int i = 0; i < 8; i++) {
    int j = tid + i * 256;
    if (j < E) s[j] = vals[i] * scaleout;
  }
}

// ---------------- weight rows (attn * v) + write fp32 wrow + split A panels ----------------
__global__ __launch_bounds__(256) void weight_split(
    const float* __restrict__ vd, int ldv, const float* __restrict__ attn,
    float* __restrict__ wrow, unsigned short* __restrict__ Apan, int M, int E) {
  const int row = blockIdx.x;
  const int r = row & 255, mt = row >> 8;
  const int c0 = threadIdx.x * 4;
  const int kt = c0 >> 5, c = c0 & 31;
  const int q = (c >> 3) ^ ((r >> 1) & 3);
  const size_t byteoff = (size_t)r * 64 + q * 16 + (c & 7) * 2;
  char* base = (char*)Apan;
  us4 hv = (us4){0, 0, 0, 0}, lv = (us4){0, 0, 0, 0};
  if (row < M) {
    const int b = row / E, e = row - b * E;
    const float a = attn[(size_t)(b * NH + (c0 >> 6)) * E + e];
    float4 v = *(const float4*)(vd + (size_t)row * ldv + c0);
    v.x *= a; v.y *= a; v.z *= a; v.w *= a;
    *(float4*)(wrow + (size_t)row * DIMK + c0) = v;
    float vv[4] = {v.x, v.y, v.z, v.w};
#pragma unroll
    for (int i = 0; i < 4; i++) {
      unsigned short hb = f32_to_bf16_rne(vv[i]);
      hv[i] = hb;
      lv[i] = f32_to_bf16_rne(vv[i] - bf16_bits_to_f32(hb));
    }
  }
  *(us4*)(base + (((size_t)(mt * 64 + kt)) << 14) + byteoff) = hv;
  *(us4*)(base + (((size_t)(mt * 64 + 32 + kt)) << 14) + byteoff) = lv;
}

// ---------------- fold duplicate-src edges into primary rows ----------------
__global__ __launch_bounds__(256) void dup_add(const int* __restrict__ f,
                                               float* __restrict__ wrow, int E) {
  const int e = blockIdx.x;
  const int fe = f[e];
  if (fe == e) return;
  const int d = threadIdx.x * 4;
#pragma unroll
  for (int b = 0; b < BB; b++) {
    const float4 v = *(const float4*)(wrow + (size_t)(b * E + e) * DIMK + d);
    float* dst = wrow + (size_t)(b * E + fe) * DIMK + d;
    atomicAdd(dst + 0, v.x);
    atomicAdd(dst + 1, v.y);
    atomicAdd(dst + 2, v.z);
    atomicAdd(dst + 3, v.w);
  }
}

// ---------------- re-split panels for primary rows that received duplicates ----------------
__global__ __launch_bounds__(256) void dup_fix(const int* __restrict__ fidx,
                                               const int* __restrict__ mark,
                                               const float* __restrict__ wrow,
                                               unsigned short* __restrict__ Apan, int E) {
  const int e = blockIdx.x;
  if (fidx[e] != e || !mark[e]) return;
  const int c0 = threadIdx.x * 4;
  const int kt = c0 >> 5, c = c0 & 31;
  char* base = (char*)Apan;
  for (int b = 0; b < BB; b++) {
    const int row = b * E + e;
    const int r = row & 255, mt = row >> 8;
    const int q = (c >> 3) ^ ((r >> 1) & 3);
    const size_t byteoff = (size_t)r * 64 + q * 16 + (c & 7) * 2;
    float4 v = *(const float4*)(wrow + (size_t)row * DIMK + c0);
    float vv[4] = {v.x, v.y, v.z, v.w};
    us4 hv, lv;
#pragma unroll
    for (int i = 0; i < 4; i++) {
      unsigned short hb = f32_to_bf16_rne(vv[i]);
      hv[i] = hb;
      lv[i] = f32_to_bf16_rne(vv[i] - bf16_bits_to_f32(hb));
    }
    *(us4*)(base + (((size_t)(mt * 64 + kt)) << 14) + byteoff) = hv;
    *(us4*)(base + (((size_t)(mt * 64 + 32 + kt)) << 14) + byteoff) = lv;
  }
}

extern "C" void kernel_launch(void* const* d_in, const int* in_sizes, int n_in,
                              void* d_out, int out_size, void* d_ws, size_t ws_size,
                              hipStream_t stream) {
  const float* x = (const float*)d_in[0];
  const int* src = (const int*)d_in[1];
  const int* dst = (const int*)d_in[2];
  const float* Wq = (const float*)d_in[3];
  const float* bq = (const float*)d_in[4];
  const float* Wk = (const float*)d_in[5];
  const float* bk = (const float*)d_in[6];
  const float* Wv = (const float*)d_in[7];
  const float* bv = (const float*)d_in[8];
  const float* Wo = (const float*)d_in[9];
  const float* bo = (const float*)d_in[10];
  const float* ew = (const float*)d_in[11];
  const float* W1 = (const float*)d_in[12];
  const float* b1 = (const float*)d_in[13];
  const float* W2 = (const float*)d_in[14];
  const float* b2 = (const float*)d_in[15];
  float* out = (float*)d_out;

  const int E = in_sizes[1];
  const int M = BB * E;
  const int gx = (M + 255) / 256;
  const int Mpad = gx * 256;
  const int mi128 = gx * 2;

  char* w = (char*)d_ws;
  float* qs = (float*)w; w += (size_t)M * DIMK * 4;
  float* kv = (float*)w; w += (size_t)M * 2048 * 4;
  float* sc = (float*)w; w += (size_t)BB * NH * E * 4;
  int* fidx = (int*)w; w += (((size_t)E * 4) + 255) & ~(size_t)255;
  int* mark = (int*)w; w += (((size_t)E * 4) + 255) & ~(size_t)255;
  float* bqf = (float*)w; w += 1024 * 4;
  float* bkf = (float*)w; w += 1024 * 4;
  unsigned short* Bq = (unsigned short*)w; w += (size_t)8 * 64 * 8192;
  unsigned short* Bkv = (unsigned short*)w; w += (size_t)16 * 64 * 8192;
  unsigned short* Bo = (unsigned short*)w; w += (size_t)8 * 64 * 8192;
  unsigned short* Apan = (unsigned short*)w; w += (size_t)gx * 64 * 16384;

  float* wrow = qs;

  // 1) fill output with bo
  const int total4 = BB * SS * (DIMK / 4);
  fill_out_kernel<<<2048, 256, 0, stream>>>((const float4*)bo, (float4*)out, total4);

  // 2) weight prep
  prep_w2<<<dim3(16, 16, 2), 256, 0, stream>>>(Wv, Wo, Bkv, Bo);
  prep_wfold<<<dim3(16, 16, 2), 256, 0, stream>>>(Wq, Wk, W1, Bq, Bkv);
  prep_bias<<<4, 256, 0, stream>>>(bq, bk, b1, W1, bqf, bkf);

  // 3) first-occurrence map + dup marks
  first_occ<<<1, 1024, 0, stream>>>(src, fidx, mark, E);

  // 4) q-part of h_pre: x_src @ WQ1 + bqf (BM=128 8-wave, grid 256)
  prep_a<<<Mpad, 256, 0, stream>>>(x, src, Apan, M, E);
  gemmT<128, 0><<<mi128 * 4, 512, 0, stream>>>(Apan, Bq, bqf, nullptr, qs, DIMK, 4,
                                               nullptr, nullptr, M, E);

  // 5) [k-part of h_pre | v]: x_dst @ [WK1 | Wv] + [bkf | bv]  (BM=256, grid 256)
  prep_a<<<Mpad, 256, 0, stream>>>(x, dst, Apan, M, E);
  gemmT<256, 0><<<gx * 8, 512, 0, stream>>>(Apan, Bkv, bkf, bv, kv, 2048, 8,
                                            nullptr, nullptr, M, E);

  // 6) edge scores (gelu + W2 dot), softmax + edge_weight
  const int CH = (E + 31) / 32;
  edge_scores_f<<<BB * NH * CH, 256, 0, stream>>>(qs, kv, W2, b2, sc, E, CH);
  softmax_ew<<<BB * NH, 256, 0, stream>>>(sc, ew, E);

  // 7) weighted rows + split panels; fold duplicates; re-split affected rows
  weight_split<<<Mpad, 256, 0, stream>>>(kv + 1024, 2048, sc, wrow, Apan, M, E);
  dup_add<<<E, 256, 0, stream>>>(fidx, wrow, E);
  dup_fix<<<E, 256, 0, stream>>>(fidx, mark, wrow, Apan, E);

  // 8) final GEMM: wrow @ Wo, guarded scatter-store (BM=128 8-wave, grid 256)
  gemmT<128, 1><<<mi128 * 4, 512, 0, stream>>>(Apan, Bo, bo, nullptr, out, DIMK, 4,
                                               fidx, src, M, E);
}